// Round 15
// baseline (256.381 us; speedup 1.0000x reference)
//
#include <hip/hip_runtime.h>
#include <hip/hip_bf16.h>
#include <stdint.h>
#include <stddef.h>

#define Bn 4
#define Sn 2048
#define En 1024
#define Hn 16
#define DIn 64
#define BSn (Bn*Sn)   // 8192
#define L2E 1.44269504089f
#define SH8L 11.5415603271f   // 8*log2(e)

typedef __attribute__((ext_vector_type(8))) short short8;
typedef __attribute__((ext_vector_type(4))) short short4v;
typedef __attribute__((ext_vector_type(4))) float fx4;
typedef __attribute__((ext_vector_type(16))) float fx16;
typedef __attribute__((ext_vector_type(8))) _Float16 half8;
typedef __attribute__((ext_vector_type(2))) __fp16 fp16x2;
typedef __attribute__((ext_vector_type(4))) int ix4;

__device__ __forceinline__ short f2bf(float f){
  union U { __hip_bfloat16 h; short s; } u; u.h = __float2bfloat16(f); return u.s;
}
__device__ __forceinline__ short f2h(float f){
  _Float16 h = (_Float16)f; return __builtin_bit_cast(short, h);
}

__device__ __forceinline__ void async16(const void* g, void* l){
  __builtin_amdgcn_global_load_lds((const __attribute__((address_space(1))) unsigned int*)g,
                                   (__attribute__((address_space(3))) unsigned int*)l, 16, 0, 0);
}

__device__ __forceinline__ fx4 mfma_bf(short8 a, short8 b, fx4 c){
  return __builtin_amdgcn_mfma_f32_16x16x32_bf16(a, b, c, 0, 0, 0);
}
__device__ __forceinline__ fx4 mfma_h(short8 a, short8 b, fx4 c){
  return __builtin_amdgcn_mfma_f32_16x16x32_f16(__builtin_bit_cast(half8, a),
                                                __builtin_bit_cast(half8, b), c, 0, 0, 0);
}
__device__ __forceinline__ fx16 mfma32h(short8 a, short8 b, fx16 c){
  return __builtin_amdgcn_mfma_f32_32x32x16_f16(__builtin_bit_cast(half8, a),
                                                __builtin_bit_cast(half8, b), c, 0, 0, 0);
}

#define FENCE asm volatile("" ::: "memory")
#define WAIT_VM6 asm volatile("s_waitcnt vmcnt(6)" ::: "memory")
#define WAIT_VM4 asm volatile("s_waitcnt vmcnt(4)" ::: "memory")
#define WAIT_VM0 asm volatile("s_waitcnt vmcnt(0)" ::: "memory")
#define WAIT_LGKM0 asm volatile("s_waitcnt lgkmcnt(0)" ::: "memory")

// ---------------- fused streaming pre-pass (BW-oriented, scan fused in) ----------------
__global__ __launch_bounds__(256) void fused_prep_k(
    const float* __restrict__ his, int* __restrict__ sidx, int* __restrict__ scnt,
    const float* __restrict__ mu, const float* __restrict__ sigma,
    const float* __restrict__ assign, const float* __restrict__ explore,
    const float* __restrict__ exploit, const int* __restrict__ mask,
    const float* __restrict__ Wq, const float* __restrict__ Wk,
    const float* __restrict__ Wv, const float* __restrict__ Wo,
    short* __restrict__ WQKV, short* __restrict__ Wof,
    short* __restrict__ Xc, float* __restrict__ a1Lc,
    _Float16* __restrict__ F, _Float16* __restrict__ G, float* __restrict__ out)
{
  __shared__ int sjl[32];
  __shared__ int wsum[4];
  const int id = blockIdx.x, tid = threadIdx.x;
  if (id < 512){
    // ---- weight cast: 8 independent fx4 per thread ----
    int u = id*256 + tid;                     // 131072 threads over 1048576 fx4 units
    fx4 v[8];
    int seg[8], off[8];
    #pragma unroll
    for (int it=0; it<8; it++){
      int i = u + it*131072;
      seg[it] = i >> 18;                      // En*En/4 = 262144
      off[it] = i & 262143;
      const float* src = (seg[it]==0)?Wq:(seg[it]==1)?Wk:(seg[it]==2)?Wv:Wo;
      v[it] = ((const fx4*)src)[off[it]];
    }
    #pragma unroll
    for (int it=0; it<8; it++){
      short4v o;
      if (seg[it] < 3) o = (short4v){ f2bf(v[it][0]), f2bf(v[it][1]), f2bf(v[it][2]), f2bf(v[it][3]) };
      else             o = (short4v){ f2h(v[it][0]),  f2h(v[it][1]),  f2h(v[it][2]),  f2h(v[it][3])  };
      if (seg[it] < 3) ((short4v*)WQKV)[(size_t)seg[it]*262144 + off[it]] = o;
      else             ((short4v*)Wof)[off[it]] = o;
    }
  } else if (id < 768){
    // ---- local mask scan + X gather + a1Lc (32 rows per block) ----
    int t = id - 512;
    int b = t >> 6, jb = t & 63;
    int j0 = jb*32;
    const int* mb = mask + (size_t)b*Sn;
    if (tid < 32) sjl[tid] = -1;
    int v[8]; int c = 0;
    #pragma unroll
    for (int j=0;j<8;j++){ v[j] = (mb[tid*8+j] == 0); c += v[j]; }
    int lane = tid&63, wv2 = tid>>6;
    int pref = c;
    #pragma unroll
    for (int m=1; m<64; m<<=1){ int o = __shfl_up(pref, m, 64); if (lane >= m) pref += o; }
    if (lane==63) wsum[wv2] = pref;
    __syncthreads();
    int wbase = 0;
    for (int wp=0; wp<wv2; wp++) wbase += wsum[wp];
    int cnt = wsum[0]+wsum[1]+wsum[2]+wsum[3];
    int pos = wbase + pref - c;               // exclusive prefix
    int* sxb = sidx + (size_t)b*Sn;
    #pragma unroll
    for (int j=0;j<8;j++){
      if (v[j]){
        int s = tid*8+j;
        if (pos >= j0 && pos < j0+32) sjl[pos - j0] = s;
        if (jb == 0) sxb[pos] = s;
        pos++;
      }
    }
    if (jb == 0 && tid == 0) scnt[b] = cnt;
    __syncthreads();
    int scp = (cnt + 127) & ~127;
    if (j0 >= scp) return;                    // block-uniform
    if (tid < 32){
      int j = j0 + tid;
      int s = sjl[tid];
      float a1 = 1.0f;
      if (s >= 0){
        float tt = 1.f + 0.5f*explore[(size_t)b*Sn + s] - 0.5f*exploit[(size_t)b*Sn + s];
        tt = fminf(fmaxf(tt, 0.5f), 2.f);
        a1 = 0.125f/tt * L2E;     // s is unmasked by construction
      }
      a1Lc[(size_t)b*Sn + j] = a1;
    }
    const float* hb = his + (size_t)b*Sn*En;
    short* Xb_ = Xc + ((size_t)b*Sn + j0)*En;
    #pragma unroll 8
    for (int r=0; r<32; r++){
      int s = sjl[r];
      short4v o;
      if (s >= 0){
        fx4 v2 = *(const fx4*)(hb + (size_t)s*En + tid*4);
        o = (short4v){ f2bf(v2[0]), f2bf(v2[1]), f2bf(v2[2]), f2bf(v2[3]) };
      } else o = (short4v){0,0,0,0};
      *(short4v*)(Xb_ + (size_t)r*En + tid*4) = o;
    }
  } else {
    // ---- F/G prep + zero masked out rows (4 rows per block) ----
    int r = (id - 768)*4 + (tid>>6);
    int lane = tid & 63;
    float muv = mu[(size_t)r*DIn + lane];
    float sgv = sigma[(size_t)r*DIn + lane];
    float sq = muv*muv, sg = sgv;
    #pragma unroll
    for (int m=32; m; m>>=1){ sq += __shfl_xor(sq,m,64); sg += __shfl_xor(sg,m,64); }
    float unc = sg*(1.f/64.f);
    #pragma unroll
    for (int cb=0; cb<128; cb+=64){
      int col = cb + lane;
      float fv, gv;
      if (col < 32){ float a = assign[(size_t)r*32 + col]; fv = 0.5f*a; gv = a; }
      else if (col < 96){ float m2 = mu[(size_t)r*DIn + (col-32)]; fv = m2*(1.f/64.f); gv = m2; }
      else if (col == 96){ fv = -sq*(1.f/128.f); gv = 1.f; }
      else if (col == 97){ fv = 1.f; gv = -(sq*(1.f/128.f) + 0.5f*unc); }
      else { fv = 0.f; gv = 0.f; }
      F[(size_t)r*128 + col] = (_Float16)fv;
      G[(size_t)r*128 + col] = (_Float16)gv;
    }
    if (mask[r]){
      fx4 z = {0.f,0.f,0.f,0.f};
      #pragma unroll
      for (int i2=0; i2<4; i2++)
        ((fx4*)(out + (size_t)r*En))[lane + 64*i2] = z;
    }
  }
}

// ======== BK=32 dbuf tile geometry (bank-spread layout) ========
// LDS addr (shorts) for (row r, chunk-field c): (r>>1)*64 + c*16 + (r&1)*8
// Stored kchunk at field c of row r = c ^ ((r>>1)&3); read applies same XOR.
// Dest slot idx: r = 2*(idx>>3)+(idx&1), c = (idx>>1)&3  (dest = idx*16B, linear)

// ---------------- fused GEMMs: QKV 128x256 tiles + bias 128x128, dense remap ----------
// QKV: each block stages one 128-row A panel and TWO 128-row W panels (n-pair):
// loads/K-step 4->6 but MFMA 16->32 (+33% intensity); A L2-rereads halve.
// LDS 48 KB -> 3 blocks/CU; valid blocks 432 QKV + 324 bias = 756 (~2.95/CU).
__global__ __launch_bounds__(256, 4) void fused_gemm_k(
    const short* __restrict__ A, const short* __restrict__ Wqkv,
    short* __restrict__ Q, short* __restrict__ K, short* __restrict__ Vt,
    const float* __restrict__ bq, const float* __restrict__ bk, const float* __restrict__ bv,
    const _Float16* __restrict__ G, const _Float16* __restrict__ F,
    _Float16* __restrict__ biasT, const float* __restrict__ a1Lc,
    const int* __restrict__ sidx, const int* __restrict__ scnt)
{
  __shared__ short sm[24576];   // A0[0,4096) A1[4096,8192) B0[8192,16384) B1[16384,24576)
  const int tid = threadIdx.x;
  const int wv = tid>>6, lane = tid&63, quad = lane>>4, l16 = lane&15;
  const int wm = (wv>>1)*64;
  // dense work map from scnt
  int mt[4], mbv[4], CQ[5], CB[5];
  {
    int cq = 0, cb = 0;
    #pragma unroll
    for (int b2=0; b2<4; b2++){
      int cnt2 = scnt[b2];
      int scp128 = (cnt2 + 127) & ~127;
      int scp64  = (cnt2 + 63) & ~63;
      mt[b2]  = scp128 >> 7;
      mbv[b2] = (scp64 + 127) >> 7;
      CQ[b2] = cq; cq += mt[b2]*12;           // 12 n-pairs of 256
      CB[b2] = cb; cb += mbv[b2]*mt[b2];
    }
    CQ[4] = cq; CB[4] = cb;
  }
  const int g = blockIdx.x;
  // A staging decode (2 slots: idx = tid, tid+256) and B wide decode (4 slots)
  int srwA[2], sgcA[2], srwB[4], sgcB[4];
  #pragma unroll
  for (int i=0; i<2; i++){
    int idx = i*256 + tid;
    srwA[i] = 2*(idx>>3) + (idx&1);
    sgcA[i] = (((idx>>1)&3) ^ ((idx>>3)&3))*8;
  }
  #pragma unroll
  for (int i=0; i<4; i++){
    int idx = i*256 + tid;
    srwB[i] = 2*(idx>>3) + (idx&1);           // [0,256)
    sgcB[i] = (((idx>>1)&3) ^ ((idx>>3)&3))*8;
  }
  // loop-invariant A read offsets
  int roffA[4];
  #pragma unroll
  for (int mi=0; mi<4; mi++){
    int row = wm + mi*16 + l16;
    roffA[mi] = (row>>1)*64 + ((quad ^ ((row>>1)&3))*16) + (row&1)*8;
  }
  short* A0 = sm;        short* A1 = sm + 4096;
  short* B0 = sm + 8192; short* B1 = sm + 16384;

  if (g < CQ[4]){
    // ================= QKV path (128x256) =================
    int b = 0;
    while (b < 3 && g >= CQ[b+1]) b++;
    int local = g - CQ[b];
    int mtile = local/12, npair = local%12;
    const int bb = b, jloc = mtile*128;
    const int m0 = bb*Sn + jloc;
    const int n0g = npair*256;
    const int seg = n0g >> 10, nloc = n0g & 1023;   // pair never crosses seg boundary
    const int wn = (wv&1)*128;
    int roffB[8];
    #pragma unroll
    for (int ni=0; ni<8; ni++){
      int row = wn + ni*16 + l16;               // [0,256)
      roffB[ni] = (row>>1)*64 + ((quad ^ ((row>>1)&3))*16) + (row&1)*8;
    }
    fx4 acc[4][8] = {};
    auto stage = [&](int kt, short* dA, short* dB){
      int k0 = kt*32;
      #pragma unroll
      for (int i=0; i<2; i++)
        async16(A + (size_t)(m0+srwA[i])*En + k0 + sgcA[i], dA + (i*256+tid)*8);
      #pragma unroll
      for (int i=0; i<4; i++)
        async16(Wqkv + (size_t)(n0g+srwB[i])*En + k0 + sgcB[i], dB + (i*256+tid)*8);
    };
    auto compute = [&](const short* cA, const short* cB){
      short8 af[4], bfr[8];
      #pragma unroll
      for (int mi=0; mi<4; mi++) af[mi]  = *(const short8*)&cA[roffA[mi]];
      #pragma unroll
      for (int ni=0; ni<8; ni++) bfr[ni] = *(const short8*)&cB[roffB[ni]];
      #pragma unroll
      for (int mi=0; mi<4; mi++)
        #pragma unroll
        for (int ni=0; ni<8; ni++)
          acc[mi][ni] = mfma_bf(af[mi], bfr[ni], acc[mi][ni]);
    };
    stage(0, A0, B0);
    for (int kt2=0; kt2<16; kt2++){
      stage(2*kt2+1, A1, B1);
      WAIT_VM6;
      __builtin_amdgcn_s_barrier(); FENCE;
      compute(A0, B0);
      WAIT_LGKM0;
      __builtin_amdgcn_s_barrier(); FENCE;
      if (kt2 < 15){ stage(2*kt2+2, A0, B0); WAIT_VM6; }
      else         { WAIT_VM0; }
      __builtin_amdgcn_s_barrier(); FENCE;
      compute(A1, B1);
      WAIT_LGKM0;
      __builtin_amdgcn_s_barrier(); FENCE;
    }
    __syncthreads();    // all staging drained; sm reusable
    const float* biasv = (seg == 0) ? bq : (seg == 1) ? bk : bv;
    if (seg < 2){
      short* C = seg ? K : Q;
      #pragma unroll
      for (int mi=0; mi<4; mi++)
        #pragma unroll
        for (int ni=0; ni<8; ni++){
          int col = nloc + wn + ni*16 + l16;
          float b0 = biasv[col];
          #pragma unroll
          for (int rg=0; rg<4; rg++){
            int row = m0 + wm + mi*16 + quad*4 + rg;
            C[(size_t)row*En + col] = f2h(acc[mi][ni][rg] + b0);
          }
        }
    } else {
      // Vt transpose in four 64-column passes; Ct = 64 x 136 shorts aliases sm
      short* Ct = sm;
      #pragma unroll
      for (int p=0; p<4; p++){
        __syncthreads();
        if ((wv&1) == (p>>1)){
          #pragma unroll
          for (int mi=0; mi<4; mi++)
            #pragma unroll
            for (int nj=0; nj<4; nj++){
              int ni = (p&1)*4 + nj;
              int lcol = nj*16 + l16;               // [0,64) within this 64-col group
              int lrow = wm + mi*16 + quad*4;
              float b0 = biasv[nloc + p*64 + lcol];
              short4v pk;
              #pragma unroll
              for (int rg=0; rg<4; rg++) pk[rg] = f2h(acc[mi][ni][rg] + b0);
              *(short4v*)&Ct[lcol*136 + lrow] = pk;
            }
        }
        __syncthreads();
        int sl = (tid&15)*8;
        #pragma unroll
        for (int e8=0; e8<4; e8++){
          int e_l = e8*16 + (tid>>4);               // [0,64)
          fx4 val = *(const fx4*)&Ct[e_l*136 + sl];
          int e_g = nloc + p*64 + e_l;
          size_t dst = ((size_t)(bb*Hn + (e_g>>6))*64 + (e_g&63))*Sn + jloc + sl;
          *(fx4*)&Vt[dst] = val;
        }
      }
    }
  } else if (g < CQ[4] + CB[4]){
    // ================= bias path (128x128, unchanged) =================
    int d = g - CQ[4];
    int b = 0;
    while (b < 3 && d >= CB[b+1]) b++;
    int local = d - CB[b];
    int mtile = local / mt[b];
    int ntile = local - mtile*mt[b];
    const int m0 = mtile*128, n0 = ntile*128;
    const int cnt = scnt[b];
    const int scp128 = (cnt + 127) & ~127;
    const int sC = scp128;                    // compacted biasT column stride
    const int wn = (wv&1)*64;
    int roffB[4];
    #pragma unroll
    for (int ni=0; ni<4; ni++){
      int row = wn + ni*16 + l16;
      roffB[ni] = (row>>1)*64 + ((quad ^ ((row>>1)&3))*16) + (row&1)*8;
    }
    fx4 acc[4][4] = {};
    const short* Gb = (const short*)G + (size_t)b*Sn*128;
    const short* Fb = (const short*)F + (size_t)b*Sn*128;
    const int* sx = sidx + (size_t)b*Sn;
    int rA[2], rB[2];
    #pragma unroll
    for (int i=0; i<2; i++){
      int gr = m0 + srwA[i];  rA[i] = (gr < cnt) ? sx[gr] : 0;   // pad -> finite; forced -inf below
      int qr = n0 + srwA[i];  rB[i] = (qr < cnt) ? sx[qr] : 0;   // pad q -> finite, discarded downstream
    }
    auto stageB = [&](int kt, short* dA, short* dB){
      int k0 = kt*32;
      #pragma unroll
      for (int i=0; i<2; i++){
        int idx = i*256 + tid;
        async16(Gb + (size_t)rA[i]*128 + k0 + sgcA[i], dA + idx*8);
        async16(Fb + (size_t)rB[i]*128 + k0 + sgcA[i], dB + idx*8);
      }
    };
    auto computeB = [&](const short* cA, const short* cB){
      short8 af[4], bfr[4];
      #pragma unroll
      for (int mi=0; mi<4; mi++) af[mi]  = *(const short8*)&cA[roffA[mi]];
      #pragma unroll
      for (int ni=0; ni<4; ni++) bfr[ni] = *(const short8*)&cB[roffB[ni]];
      #pragma unroll
      for (int mi=0; mi<4; mi++)
        #pragma unroll
        for (int ni=0; ni<4; ni++)
          acc[mi][ni] = mfma_h(af[mi], bfr[ni], acc[mi][ni]);
    };
    stageB(0, A0, B0);
    stageB(1, A1, B1); WAIT_VM4;
    __builtin_amdgcn_s_barrier(); FENCE;
    computeB(A0, B0); WAIT_LGKM0;
    __builtin_amdgcn_s_barrier(); FENCE;
    stageB(2, A0, B0); WAIT_VM4;
    __builtin_amdgcn_s_barrier(); FENCE;
    computeB(A1, B1); WAIT_LGKM0;
    __builtin_amdgcn_s_barrier(); FENCE;
    stageB(3, A1, B1); WAIT_VM4;
    __builtin_amdgcn_s_barrier(); FENCE;
    computeB(A0, B0); WAIT_LGKM0;
    __builtin_amdgcn_s_barrier(); FENCE;
    WAIT_VM0;
    __builtin_amdgcn_s_barrier(); FENCE;
    computeB(A1, B1);
    _Float16* bQ = biasT + (size_t)b*Sn*Sn;
    #pragma unroll
    for (int mi=0; mi<4; mi++)
      #pragma unroll
      for (int ni=0; ni<4; ni++){
        int col = n0 + wn + ni*16 + l16;          // compacted q
        int rowb = m0 + wm + mi*16 + quad*4;      // compacted s base
        float s8 = 8.f * a1Lc[b*Sn + col];
        short4v pk;
        #pragma unroll
        for (int rg=0; rg<4; rg++){
          int s = rowb + rg;
          short hv;
          if (s >= cnt) hv = (short)0xFC00;       // -inf for pad key rows
          else hv = f2h(acc[mi][ni][rg]*s8 - SH8L);
          pk[rg] = hv;
        }
        *(short4v*)&bQ[((size_t)(rowb>>3)*sC + col)*8 + (rowb&7)] = pk;
      }
  }
}

// ---------------- output projection: dense remap, 128x128 tiles ----------------
__global__ __launch_bounds__(256, 4) void gemm_out_k(
    const short* __restrict__ A, const short* __restrict__ Bm, float* __restrict__ C,
    const float* __restrict__ biasv, const int* __restrict__ sidx, const int* __restrict__ scnt)
{
  __shared__ short sm[16384];
  const int tid = threadIdx.x;
  const int wv = tid>>6, lane = tid&63, quad = lane>>4, l16 = lane&15;
  int mt[4], CO[5];
  {
    int co = 0;
    #pragma unroll
    for (int b2=0; b2<4; b2++){
      mt[b2] = ((scnt[b2] + 127) & ~127) >> 7;
      CO[b2] = co; co += mt[b2]*8;
    }
    CO[4] = co;
  }
  const int g = blockIdx.x;
  if (g >= CO[4]) return;
  int b = 0;
  while (b < 3 && g >= CO[b+1]) b++;
  int local = g - CO[b];
  int mtile = local >> 3, ntile = local & 7;
  const int jloc = mtile*128, n0 = ntile*128;
  const int m0 = b*Sn + jloc;
  const int cnt = scnt[b];
  const int* sx = sidx + (size_t)b*Sn;
  const int wm = (wv>>1)*64, wn = (wv&1)*64;
  int srw[2], sgc[2];
  #pragma unroll
  for (int i=0; i<2; i++){
    int idx = i*256 + tid;
    srw[i] = 2*(idx>>3) + (idx&1);
    sgc[i] = (((idx>>1)&3) ^ ((idx>>3)&3))*8;
  }
  auto stage = [&](int kt, short* dA, short* dB){
    int k0 = kt*32;
    #pragma unroll
    for (int i=0; i<2; i++){
      int idx = i*256 + tid;
      async16(A  + (size_t)(m0+srw[i])*En + k0 + sgc[i], dA + idx*8);
      async16(Bm + (size_t)(n0+srw[i])*En + k0 + sgc[i], dB + idx*8);
    }
  };
  fx4 acc[4][4] = {};
  int roffA[4], roffB[4];
  #pragma unroll
  for (int mi=0; mi<4; mi++){
    int row = wm + mi*16 + l16;
    roffA[mi] = (row>>1)*64 + ((quad ^ ((row>>1)&3))*16) + (row&1)*8;
    int rowb = wn + mi*16 + l16;
    roffB[mi] = (rowb>>1)*64 + ((quad ^ ((rowb>>1)&3))*16) + (rowb&1)*8;
  }
  auto compute = [&](const short* cA, const short* cB){
    short8 af[4], bfr[4];
    #pragma unroll
    for (int mi=0; mi<4; mi++) af[mi]  = *(const short8*)&cA[roffA[mi]];
    #pragma unroll
    for (int ni=0; ni<4; ni++) bfr[ni] = *(const short8*)&cB[roffB[ni]];
    #pragma unroll
    for (int mi=0; mi<4; mi++)
      #pragma unroll
      for (int ni=0; ni<4; ni++)
        acc[mi][ni] = mfma_h(af[mi], bfr[ni], acc[mi][ni]);
  };
  stage(0, sm, sm+8192);
  for (int kt2=0; kt2<16; kt2++){
    stage(2*kt2+1, sm+4096, sm+12288);
    WAIT_VM4;
    __builtin_amdgcn_s_barrier(); FENCE;
    compute(sm, sm+8192);
    WAIT_LGKM0;
    __builtin_amdgcn_s_barrier(); FENCE;
    if (kt2 < 15){ stage(2*kt2+2, sm, sm+8192); WAIT_VM4; }
    else         { WAIT_VM0; }
    __builtin_amdgcn_s_barrier(); FENCE;
    compute(sm+4096, sm+12288);
    WAIT_LGKM0;
    __builtin_amdgcn_s_barrier(); FENCE;
  }
  #pragma unroll
  for (int mi=0; mi<4; mi++)
    #pragma unroll
    for (int ni=0; ni<4; ni++)
      #pragma unroll
      for (int rg=0; rg<4; rg++){
        int j = jloc + wm + mi*16 + quad*4 + rg;
        if (j < cnt){
          int row = b*Sn + sx[j];
          int col = n0 + wn + ni*16 + l16;
          C[(size_t)row*En + col] = acc[mi][ni][rg] + biasv[col];
        }
      }
}

// ---------------- flash attention v8: compacted + XCD-grouped block mapping ----------
__global__ __launch_bounds__(256, 4) void flash8_k(
    const short* __restrict__ Qg, const short* __restrict__ Kg, const short* __restrict__ Vtg,
    const _Float16* __restrict__ biasB, const float* __restrict__ a1Lv,
    const int* __restrict__ scnt, short* __restrict__ AO)
{
  __shared__ short smem[2][2][64*64];   // [buf][K/Vt][tile] = 32 KB
  const int tid = threadIdx.x, wv = tid>>6, lane = tid&63;
  const int l32 = lane&31, hi = lane>>5;
  const int lid = blockIdx.x;
  const int bh = (lid & 7)*8 + ((lid >> 3) & 7);
  const int q0 = (lid >> 6)*128;
  const int b = bh >> 4, h = bh & 15;
  const int cnt = scnt[b];
  const int NT = ((cnt + 63) & ~63) >> 6;       // compacted key tile count
  const int scp128 = (cnt + 127) & ~127;
  if (q0 >= scp128) return;                     // compacted query blocks only
  const int sC = scp128;                        // compacted biasT column stride
  const short* Qb  = Qg  + (size_t)b*Sn*En + h*64;
  const int q = q0 + wv*32 + l32;
  const float a1L = a1Lv[b*Sn + q];

  // thread-fixed staging coords (rnd1 = rnd0 + 32 rows; col swizzle identical)
  const int r0 = tid>>3, c0 = (tid&7) ^ (r0&7);
  const int kr0 = (r0 & 51) | ((r0&4)<<1) | ((r0&8)>>1);   // s-bits 2<->3 swap
  const short* kA = Kg  + (size_t)b*Sn*En + h*64 + (size_t)kr0*En + c0*8;
  const short* vA = Vtg + (size_t)(b*Hn + h)*64*Sn + (size_t)r0*Sn + c0*8;
  const _Float16* bP = biasB + (size_t)b*Sn*Sn + ((size_t)hi*sC + q)*8;
  const int ld0 = tid*8;   // LDS slot (shorts), rnd1 = +2048

  auto issue = [&](int buf){
    short* base = &smem[buf][0][0];
    async16(kA,             base + ld0);
    async16(kA + 32*En,     base + 2048 + ld0);
    async16(vA,             base + 4096 + ld0);
    async16(vA + 32*Sn,     base + 4096 + 2048 + ld0);
  };
  if (NT > 0){ issue(0); }
  kA += 64*En; vA += 64;

  // Q B-frags: B[n=q][k = c*16 + hi*8 + j]
  short8 qf[4];
  #pragma unroll
  for (int c=0; c<4; c++)
    qf[c] = *(const short8*)(Qb + (size_t)q*En + c*16 + hi*8);

  // loop-invariant LDS read offsets (shorts), K plane / V plane
  int koff[2][4], voff[2][4];
  #pragma unroll
  for (int t=0; t<2; t++){
    int m = t*32 + l32;
    #pragma unroll
    for (int c=0; c<4; c++)
      koff[t][c] = m*64 + (((c*2 + hi) ^ (m&7))*8);
  }
  #pragma unroll
  for (int ds=0; ds<2; ds++){
    int rv = ds*32 + l32;
    #pragma unroll
    for (int sc=0; sc<4; sc++)
      voff[ds][sc] = 4096 + rv*64 + (((sc*2 + hi) ^ (rv&7))*8);
  }

  fp16x2 one2; one2[0] = (__fp16)1.0f; one2[1] = (__fp16)1.0f;
  fx16 o0 = {}, o1 = {};
  float psum = 0.f;

  for (int T=0; T<NT; T++){
    __syncthreads();                      // tile T resident; other buf free
    const short* base = &smem[T&1][0][0];
    if (T < NT-1){ issue((T&1)^1); kA += 64*En; vA += 64; }

    #pragma unroll
    for (int t=0; t<2; t++){              // s-strip of 32
      half8 bch[2];
      #pragma unroll
      for (int c2=0; c2<2; c2++)
        bch[c2] = *(const half8*)(bP + (size_t)(t*4 + c2*2)*sC*8);
      fx16 sa = {};
      #pragma unroll
      for (int c=0; c<4; c++){
        short8 ka = *(const short8*)(base + koff[t][c]);
        sa = mfma32h(ka, qf[c], sa);
      }
      #pragma unroll
      for (int c2=0; c2<2; c2++){
        fp16x2 pk_[4];
        #pragma unroll
        for (int jj=0; jj<4; jj++){
          float pa = __builtin_amdgcn_exp2f(fmaf(sa[c2*8 + jj*2],     a1L, (float)bch[c2][jj*2]));
          float pb = __builtin_amdgcn_exp2f(fmaf(sa[c2*8 + jj*2 + 1], a1L, (float)bch[c2][jj*2+1]));
          pk_[jj] = __builtin_amdgcn_cvt_pkrtz(pa, pb);
          psum = __builtin_amdgcn_fdot2(pk_[jj], one2, psum, false);
        }
        ix4 fr = { __builtin_bit_cast(int, pk_[0]), __builtin_bit_cast(int, pk_[1]),
                   __builtin_bit_cast(int, pk_[2]), __builtin_bit_cast(int, pk_[3]) };
        short8 pfr = __builtin_bit_cast(short8, fr);
        int sc = t*2 + c2;
        #pragma unroll
        for (int ds=0; ds<2; ds++){
          short8 va = *(const short8*)(base + voff[ds][sc]);
          if (ds == 0) o0 = mfma32h(va, pfr, o0);
          else         o1 = mfma32h(va, pfr, o1);
        }
      }
    }
    bP += (size_t)8*sC*8;
  }

  psum += __shfl_xor(psum, 32, 64);
  float linv = 1.f/fmaxf(psum, 1e-30f);

  // epilogue: stage o^T -> LDS [q][d] (stride 72), then coalesced b128 stores
  __syncthreads();
  short* stage = &smem[0][0][0] + wv*2304;   // 32*72 shorts per wave
  #pragma unroll
  for (int ds=0; ds<2; ds++){
    const fx16& o = ds ? o1 : o0;
    #pragma unroll
    for (int rq=0; rq<4; rq++){
      int d0 = ds*32 + rq*8 + hi*4;
      short4v pk;
      #pragma unroll
      for (int j=0; j<4; j++) pk[j] = f2h(o[rq*4 + j]*linv);
      *(short4v*)&stage[l32*72 + d0] = pk;
    }
  }
  short* AOb = AO + (size_t)b*Sn*En + h*64;
  #pragma unroll
  for (int rnd=0; rnd<4; rnd++){
    int idx = rnd*64 + lane;
    int r = idx>>3, ch = idx&7;
    fx4 val = *(const fx4*)&stage[r*72 + ch*8];
    *(fx4*)(AOb + (size_t)(q0 + wv*32 + r)*En + ch*8) = val;
  }
}

extern "C" void kernel_launch(void* const* d_in, const int* in_sizes, int n_in,
                              void* d_out, int out_size, void* d_ws, size_t ws_size,
                              hipStream_t stream)
{
  const float* his     = (const float*)d_in[0];
  const int*   mask    = (const int*)  d_in[1];
  const float* mu      = (const float*)d_in[2];
  const float* sigma   = (const float*)d_in[3];
  const float* assign  = (const float*)d_in[4];
  const float* explore = (const float*)d_in[5];
  const float* exploit = (const float*)d_in[6];
  const float* Wq = (const float*)d_in[7];  const float* bq = (const float*)d_in[8];
  const float* Wk = (const float*)d_in[9];  const float* bk = (const float*)d_in[10];
  const float* Wv = (const float*)d_in[11]; const float* bv = (const float*)d_in[12];
  const float* Wo = (const float*)d_in[13]; const float* bo = (const float*)d_in[14];

  char* w = (char*)d_ws;
  size_t off = 0;
  auto alloc = [&](size_t bytes){ void* p = w + off; off += (bytes + 255) & ~(size_t)255; return p; };
  short*     Xc    = (short*)alloc((size_t)BSn*En*2);
  short*     WQKV  = (short*)alloc((size_t)3*En*En*2);
  short*     Wof   = (short*)alloc((size_t)En*En*2);
  short*     Qc    = (short*)alloc((size_t)BSn*En*2);
  short*     Kc    = (short*)alloc((size_t)BSn*En*2);
  short*     Vtc   = (short*)alloc((size_t)BSn*En*2);
  short*     AO    = (short*)alloc((size_t)BSn*En*2);
  _Float16*  F     = (_Float16*)alloc((size_t)BSn*128*2);
  _Float16*  G     = (_Float16*)alloc((size_t)BSn*128*2);
  _Float16*  biasT = (_Float16*)alloc((size_t)Bn*Sn*Sn*2);
  float*     a1Lc  = (float*)alloc((size_t)BSn*4);
  int*       sidx  = (int*)alloc((size_t)BSn*4);
  int*       scnt  = (int*)alloc(256);
  (void)ws_size; (void)in_sizes; (void)n_in; (void)out_size;

  fused_prep_k<<<2816, 256, 0, stream>>>(his, sidx, scnt, mu, sigma, assign, explore, exploit,
                                         mask, Wq, Wk, Wv, Wo, WQKV, Wof, Xc, a1Lc, F, G,
                                         (float*)d_out);
  fused_gemm_k<<<1280, 256, 0, stream>>>(Xc, WQKV, Qc, Kc, Vtc, bq, bk, bv,
                                         (const _Float16*)G, (const _Float16*)F,
                                         biasT, a1Lc, sidx, scnt);
  flash8_k<<<1024, 256, 0, stream>>>(Qc, Kc, Vtc, biasT, a1Lc, scnt, AO);
  gemm_out_k<<<512, 256, 0, stream>>>(AO, Wof, (float*)d_out, bo, sidx, scnt);
}

// Round 16
// 251.259 us; speedup vs baseline: 1.0204x; 1.0204x over previous
//
#include <hip/hip_runtime.h>
#include <hip/hip_bf16.h>
#include <stdint.h>
#include <stddef.h>

#define Bn 4
#define Sn 2048
#define En 1024
#define Hn 16
#define DIn 64
#define BSn (Bn*Sn)   // 8192
#define L2E 1.44269504089f
#define SH8L 11.5415603271f   // 8*log2(e)

typedef __attribute__((ext_vector_type(8))) short short8;
typedef __attribute__((ext_vector_type(4))) short short4v;
typedef __attribute__((ext_vector_type(4))) float fx4;
typedef __attribute__((ext_vector_type(16))) float fx16;
typedef __attribute__((ext_vector_type(8))) _Float16 half8;
typedef __attribute__((ext_vector_type(2))) __fp16 fp16x2;
typedef __attribute__((ext_vector_type(4))) int ix4;

__device__ __forceinline__ short f2bf(float f){
  union U { __hip_bfloat16 h; short s; } u; u.h = __float2bfloat16(f); return u.s;
}
__device__ __forceinline__ short f2h(float f){
  _Float16 h = (_Float16)f; return __builtin_bit_cast(short, h);
}

__device__ __forceinline__ void async16(const void* g, void* l){
  __builtin_amdgcn_global_load_lds((const __attribute__((address_space(1))) unsigned int*)g,
                                   (__attribute__((address_space(3))) unsigned int*)l, 16, 0, 0);
}

__device__ __forceinline__ fx4 mfma_bf(short8 a, short8 b, fx4 c){
  return __builtin_amdgcn_mfma_f32_16x16x32_bf16(a, b, c, 0, 0, 0);
}
__device__ __forceinline__ fx4 mfma_h(short8 a, short8 b, fx4 c){
  return __builtin_amdgcn_mfma_f32_16x16x32_f16(__builtin_bit_cast(half8, a),
                                                __builtin_bit_cast(half8, b), c, 0, 0, 0);
}
__device__ __forceinline__ fx16 mfma32h(short8 a, short8 b, fx16 c){
  return __builtin_amdgcn_mfma_f32_32x32x16_f16(__builtin_bit_cast(half8, a),
                                                __builtin_bit_cast(half8, b), c, 0, 0, 0);
}

#define FENCE asm volatile("" ::: "memory")
#define WAIT_VM4 asm volatile("s_waitcnt vmcnt(4)" ::: "memory")
#define WAIT_VM0 asm volatile("s_waitcnt vmcnt(0)" ::: "memory")
#define WAIT_LGKM0 asm volatile("s_waitcnt lgkmcnt(0)" ::: "memory")

// ---------------- fused streaming pre-pass (BW-oriented, scan fused in) ----------------
// ids [0,512):      weight cast, grid-stride 8 fx4/thread
// ids [512,768):    mask scan (local) + gather+cast X rows (32 rows/block) + a1Lc;
//                   jb==0 block per batch also materializes sidx/scnt for downstream
// ids [768,2816):   F/G row prep + zero masked output rows (4 rows/block)
__global__ __launch_bounds__(256) void fused_prep_k(
    const float* __restrict__ his, int* __restrict__ sidx, int* __restrict__ scnt,
    const float* __restrict__ mu, const float* __restrict__ sigma,
    const float* __restrict__ assign, const float* __restrict__ explore,
    const float* __restrict__ exploit, const int* __restrict__ mask,
    const float* __restrict__ Wq, const float* __restrict__ Wk,
    const float* __restrict__ Wv, const float* __restrict__ Wo,
    short* __restrict__ WQKV, short* __restrict__ Wof,
    short* __restrict__ Xc, float* __restrict__ a1Lc,
    _Float16* __restrict__ F, _Float16* __restrict__ G, float* __restrict__ out)
{
  __shared__ int sjl[32];
  __shared__ int wsum[4];
  const int id = blockIdx.x, tid = threadIdx.x;
  if (id < 512){
    // ---- weight cast: 8 independent fx4 per thread ----
    int u = id*256 + tid;                     // 131072 threads over 1048576 fx4 units
    fx4 v[8];
    int seg[8], off[8];
    #pragma unroll
    for (int it=0; it<8; it++){
      int i = u + it*131072;
      seg[it] = i >> 18;                      // En*En/4 = 262144
      off[it] = i & 262143;
      const float* src = (seg[it]==0)?Wq:(seg[it]==1)?Wk:(seg[it]==2)?Wv:Wo;
      v[it] = ((const fx4*)src)[off[it]];
    }
    #pragma unroll
    for (int it=0; it<8; it++){
      short4v o;
      if (seg[it] < 3) o = (short4v){ f2bf(v[it][0]), f2bf(v[it][1]), f2bf(v[it][2]), f2bf(v[it][3]) };
      else             o = (short4v){ f2h(v[it][0]),  f2h(v[it][1]),  f2h(v[it][2]),  f2h(v[it][3])  };
      if (seg[it] < 3) ((short4v*)WQKV)[(size_t)seg[it]*262144 + off[it]] = o;
      else             ((short4v*)Wof)[off[it]] = o;
    }
  } else if (id < 768){
    // ---- local mask scan + X gather + a1Lc (32 rows per block) ----
    int t = id - 512;
    int b = t >> 6, jb = t & 63;
    int j0 = jb*32;
    const int* mb = mask + (size_t)b*Sn;
    if (tid < 32) sjl[tid] = -1;
    int v[8]; int c = 0;
    #pragma unroll
    for (int j=0;j<8;j++){ v[j] = (mb[tid*8+j] == 0); c += v[j]; }
    int lane = tid&63, wv2 = tid>>6;
    int pref = c;
    #pragma unroll
    for (int m=1; m<64; m<<=1){ int o = __shfl_up(pref, m, 64); if (lane >= m) pref += o; }
    if (lane==63) wsum[wv2] = pref;
    __syncthreads();
    int wbase = 0;
    for (int wp=0; wp<wv2; wp++) wbase += wsum[wp];
    int cnt = wsum[0]+wsum[1]+wsum[2]+wsum[3];
    int pos = wbase + pref - c;               // exclusive prefix
    int* sxb = sidx + (size_t)b*Sn;
    #pragma unroll
    for (int j=0;j<8;j++){
      if (v[j]){
        int s = tid*8+j;
        if (pos >= j0 && pos < j0+32) sjl[pos - j0] = s;
        if (jb == 0) sxb[pos] = s;
        pos++;
      }
    }
    if (jb == 0 && tid == 0) scnt[b] = cnt;
    __syncthreads();
    int scp = (cnt + 127) & ~127;
    if (j0 >= scp) return;                    // block-uniform
    if (tid < 32){
      int j = j0 + tid;
      int s = sjl[tid];
      float a1 = 1.0f;
      if (s >= 0){
        float tt = 1.f + 0.5f*explore[(size_t)b*Sn + s] - 0.5f*exploit[(size_t)b*Sn + s];
        tt = fminf(fmaxf(tt, 0.5f), 2.f);
        a1 = 0.125f/tt * L2E;     // s is unmasked by construction
      }
      a1Lc[(size_t)b*Sn + j] = a1;
    }
    const float* hb = his + (size_t)b*Sn*En;
    short* Xb_ = Xc + ((size_t)b*Sn + j0)*En;
    #pragma unroll 8
    for (int r=0; r<32; r++){
      int s = sjl[r];
      short4v o;
      if (s >= 0){
        fx4 v2 = *(const fx4*)(hb + (size_t)s*En + tid*4);
        o = (short4v){ f2bf(v2[0]), f2bf(v2[1]), f2bf(v2[2]), f2bf(v2[3]) };
      } else o = (short4v){0,0,0,0};
      *(short4v*)(Xb_ + (size_t)r*En + tid*4) = o;
    }
  } else {
    // ---- F/G prep + zero masked out rows (4 rows per block) ----
    int r = (id - 768)*4 + (tid>>6);
    int lane = tid & 63;
    float muv = mu[(size_t)r*DIn + lane];
    float sgv = sigma[(size_t)r*DIn + lane];
    float sq = muv*muv, sg = sgv;
    #pragma unroll
    for (int m=32; m; m>>=1){ sq += __shfl_xor(sq,m,64); sg += __shfl_xor(sg,m,64); }
    float unc = sg*(1.f/64.f);
    #pragma unroll
    for (int cb=0; cb<128; cb+=64){
      int col = cb + lane;
      float fv, gv;
      if (col < 32){ float a = assign[(size_t)r*32 + col]; fv = 0.5f*a; gv = a; }
      else if (col < 96){ float m2 = mu[(size_t)r*DIn + (col-32)]; fv = m2*(1.f/64.f); gv = m2; }
      else if (col == 96){ fv = -sq*(1.f/128.f); gv = 1.f; }
      else if (col == 97){ fv = 1.f; gv = -(sq*(1.f/128.f) + 0.5f*unc); }
      else { fv = 0.f; gv = 0.f; }
      F[(size_t)r*128 + col] = (_Float16)fv;
      G[(size_t)r*128 + col] = (_Float16)gv;
    }
    if (mask[r]){
      fx4 z = {0.f,0.f,0.f,0.f};
      #pragma unroll
      for (int i2=0; i2<4; i2++)
        ((fx4*)(out + (size_t)r*En))[lane + 64*i2] = z;
    }
  }
}

// ======== BK=32 dbuf tile geometry (bank-spread layout) ========
// LDS addr (shorts) for (row r, chunk-field c): (r>>1)*64 + c*16 + (r&1)*8
// Stored kchunk at field c of row r = c ^ ((r>>1)&3); read applies same XOR.
// Dest slot idx: r = 2*(idx>>3)+(idx&1), c = (idx>>1)&3  (dest = idx*16B, linear)

// ---------------- fused independent GEMMs: QKV + bias, DENSE work remap ----------------
// Valid (b, mtile, ntile) work items are packed densely at the front of blockIdx space
// (QKV items first, then bias items); invalid blocks all sit at the tail -> no CU gets
// starved by clustered early-exit runs. 128x128 tiles (verified optimum, R14).
__global__ __launch_bounds__(256, 4) void fused_gemm_k(
    const short* __restrict__ A, const short* __restrict__ Wqkv,
    short* __restrict__ Q, short* __restrict__ K, short* __restrict__ Vt,
    const float* __restrict__ bq, const float* __restrict__ bk, const float* __restrict__ bv,
    const _Float16* __restrict__ G, const _Float16* __restrict__ F,
    _Float16* __restrict__ biasT, const float* __restrict__ a1Lc,
    const int* __restrict__ sidx, const int* __restrict__ scnt)
{
  __shared__ short sm[16384];   // A0[0,4096) A1[4096,8192) B0[8192,12288) B1[12288,16384)
  const int tid = threadIdx.x;
  const int wv = tid>>6, lane = tid&63, quad = lane>>4, l16 = lane&15;
  const int wm = (wv>>1)*64, wn = (wv&1)*64;
  // dense work map from scnt
  int mt[4], mbv[4], CQ[5], CB[5];
  {
    int cq = 0, cb = 0;
    #pragma unroll
    for (int b2=0; b2<4; b2++){
      int cnt2 = scnt[b2];
      int scp128 = (cnt2 + 127) & ~127;
      int scp64  = (cnt2 + 63) & ~63;
      mt[b2]  = scp128 >> 7;
      mbv[b2] = (scp64 + 127) >> 7;
      CQ[b2] = cq; cq += mt[b2]*24;
      CB[b2] = cb; cb += mbv[b2]*mt[b2];
    }
    CQ[4] = cq; CB[4] = cb;
  }
  const int g = blockIdx.x;
  // per-thread staging decode (2 slots: idx = tid, tid+256)
  int srw[2], sgc[2];
  #pragma unroll
  for (int i=0; i<2; i++){
    int idx = i*256 + tid;
    srw[i] = 2*(idx>>3) + (idx&1);
    sgc[i] = (((idx>>1)&3) ^ ((idx>>3)&3))*8;
  }
  // loop-invariant read offsets (shorts)
  int roffA[4], roffB[4];
  #pragma unroll
  for (int mi=0; mi<4; mi++){
    int row = wm + mi*16 + l16;
    roffA[mi] = (row>>1)*64 + ((quad ^ ((row>>1)&3))*16) + (row&1)*8;
    int rowb = wn + mi*16 + l16;
    roffB[mi] = (rowb>>1)*64 + ((quad ^ ((rowb>>1)&3))*16) + (rowb&1)*8;
  }
  short* A0 = sm;       short* A1 = sm + 4096;
  short* B0 = sm + 8192; short* B1 = sm + 12288;
  fx4 acc[4][4] = {};

  if (g < CQ[4]){
    // ================= QKV path (dense) =================
    int b = 0;
    while (b < 3 && g >= CQ[b+1]) b++;
    int local = g - CQ[b];
    int mtile = local/24, ntile = local%24;
    const int bb = b, jloc = mtile*128;
    const int m0 = bb*Sn + jloc;
    const int n0g = ntile*128;
    const int seg = n0g >> 10, nloc = n0g & 1023;
    auto stage = [&](int kt, short* dA, short* dB){
      int k0 = kt*32;
      #pragma unroll
      for (int i=0; i<2; i++){
        int idx = i*256 + tid;
        async16(A    + (size_t)(m0+srw[i])*En  + k0 + sgc[i], dA + idx*8);
        async16(Wqkv + (size_t)(n0g+srw[i])*En + k0 + sgc[i], dB + idx*8);
      }
    };
    auto compute = [&](const short* cA, const short* cB){
      short8 af[4], bfr[4];
      #pragma unroll
      for (int mi=0; mi<4; mi++) af[mi]  = *(const short8*)&cA[roffA[mi]];
      #pragma unroll
      for (int ni=0; ni<4; ni++) bfr[ni] = *(const short8*)&cB[roffB[ni]];
      #pragma unroll
      for (int mi=0; mi<4; mi++)
        #pragma unroll
        for (int ni=0; ni<4; ni++)
          acc[mi][ni] = mfma_bf(af[mi], bfr[ni], acc[mi][ni]);
    };
    stage(0, A0, B0);
    for (int kt2=0; kt2<16; kt2++){
      stage(2*kt2+1, A1, B1);
      WAIT_VM4;
      __builtin_amdgcn_s_barrier(); FENCE;
      compute(A0, B0);
      WAIT_LGKM0;
      __builtin_amdgcn_s_barrier(); FENCE;
      if (kt2 < 15){ stage(2*kt2+2, A0, B0); WAIT_VM4; }
      else         { WAIT_VM0; }
      __builtin_amdgcn_s_barrier(); FENCE;
      compute(A1, B1);
      WAIT_LGKM0;
      __builtin_amdgcn_s_barrier(); FENCE;
    }
    __syncthreads();    // all staging drained; sm reusable
    const float* biasv = (seg == 0) ? bq : (seg == 1) ? bk : bv;
    if (seg < 2){
      short* C = seg ? K : Q;
      #pragma unroll
      for (int mi=0; mi<4; mi++)
        #pragma unroll
        for (int ni=0; ni<4; ni++){
          int col = nloc + wn + ni*16 + l16;
          float b0 = biasv[col];
          #pragma unroll
          for (int rg=0; rg<4; rg++){
            int row = m0 + wm + mi*16 + quad*4 + rg;
            C[(size_t)row*En + col] = f2h(acc[mi][ni][rg] + b0);
          }
        }
    } else {
      // Vt transpose in two 64-column passes; Ct2 = 64 x 136 shorts aliases sm
      short* Ct = sm;
      #pragma unroll
      for (int p=0; p<2; p++){
        __syncthreads();
        if ((wv&1) == p){
          #pragma unroll
          for (int mi=0; mi<4; mi++)
            #pragma unroll
            for (int ni=0; ni<4; ni++){
              int lcol = ni*16 + l16;               // [0,64) within this half
              int lrow = wm + mi*16 + quad*4;
              float b0 = biasv[nloc + p*64 + lcol];
              short4v pk;
              #pragma unroll
              for (int rg=0; rg<4; rg++) pk[rg] = f2h(acc[mi][ni][rg] + b0);
              *(short4v*)&Ct[lcol*136 + lrow] = pk;
            }
        }
        __syncthreads();
        int sl = (tid&15)*8;
        #pragma unroll
        for (int e8=0; e8<4; e8++){
          int e_l = e8*16 + (tid>>4);               // [0,64)
          fx4 val = *(const fx4*)&Ct[e_l*136 + sl];
          int e_g = nloc + p*64 + e_l;
          size_t dst = ((size_t)(bb*Hn + (e_g>>6))*64 + (e_g&63))*Sn + jloc + sl;
          *(fx4*)&Vt[dst] = val;
        }
      }
    }
  } else if (g < CQ[4] + CB[4]){
    // ================= bias path (dense) =================
    int d = g - CQ[4];
    int b = 0;
    while (b < 3 && d >= CB[b+1]) b++;
    int local = d - CB[b];
    int mtile = local / mt[b];
    int ntile = local - mtile*mt[b];
    const int m0 = mtile*128, n0 = ntile*128;
    const int cnt = scnt[b];
    const int scp128 = (cnt + 127) & ~127;
    const int sC = scp128;                    // compacted biasT column stride
    const short* Gb = (const short*)G + (size_t)b*Sn*128;
    const short* Fb = (const short*)F + (size_t)b*Sn*128;
    const int* sx = sidx + (size_t)b*Sn;
    int rA[2], rB[2];
    #pragma unroll
    for (int i=0; i<2; i++){
      int gr = m0 + srw[i];  rA[i] = (gr < cnt) ? sx[gr] : 0;   // pad -> finite; forced -inf below
      int qr = n0 + srw[i];  rB[i] = (qr < cnt) ? sx[qr] : 0;   // pad q -> finite, discarded downstream
    }
    auto stageB = [&](int kt, short* dA, short* dB){
      int k0 = kt*32;
      #pragma unroll
      for (int i=0; i<2; i++){
        int idx = i*256 + tid;
        async16(Gb + (size_t)rA[i]*128 + k0 + sgc[i], dA + idx*8);
        async16(Fb + (size_t)rB[i]*128 + k0 + sgc[i], dB + idx*8);
      }
    };
    auto computeB = [&](const short* cA, const short* cB){
      short8 af[4], bfr[4];
      #pragma unroll
      for (int mi=0; mi<4; mi++) af[mi]  = *(const short8*)&cA[roffA[mi]];
      #pragma unroll
      for (int ni=0; ni<4; ni++) bfr[ni] = *(const short8*)&cB[roffB[ni]];
      #pragma unroll
      for (int mi=0; mi<4; mi++)
        #pragma unroll
        for (int ni=0; ni<4; ni++)
          acc[mi][ni] = mfma_h(af[mi], bfr[ni], acc[mi][ni]);
    };
    stageB(0, A0, B0);
    stageB(1, A1, B1); WAIT_VM4;
    __builtin_amdgcn_s_barrier(); FENCE;
    computeB(A0, B0); WAIT_LGKM0;
    __builtin_amdgcn_s_barrier(); FENCE;
    stageB(2, A0, B0); WAIT_VM4;
    __builtin_amdgcn_s_barrier(); FENCE;
    computeB(A1, B1); WAIT_LGKM0;
    __builtin_amdgcn_s_barrier(); FENCE;
    stageB(3, A1, B1); WAIT_VM4;
    __builtin_amdgcn_s_barrier(); FENCE;
    computeB(A0, B0); WAIT_LGKM0;
    __builtin_amdgcn_s_barrier(); FENCE;
    WAIT_VM0;
    __builtin_amdgcn_s_barrier(); FENCE;
    computeB(A1, B1);
    _Float16* bQ = biasT + (size_t)b*Sn*Sn;
    #pragma unroll
    for (int mi=0; mi<4; mi++)
      #pragma unroll
      for (int ni=0; ni<4; ni++){
        int col = n0 + wn + ni*16 + l16;          // compacted q
        int rowb = m0 + wm + mi*16 + quad*4;      // compacted s base
        float s8 = 8.f * a1Lc[b*Sn + col];
        short4v pk;
        #pragma unroll
        for (int rg=0; rg<4; rg++){
          int s = rowb + rg;
          short hv;
          if (s >= cnt) hv = (short)0xFC00;       // -inf for pad key rows
          else hv = f2h(acc[mi][ni][rg]*s8 - SH8L);
          pk[rg] = hv;
        }
        *(short4v*)&bQ[((size_t)(rowb>>3)*sC + col)*8 + (rowb&7)] = pk;
      }
  }
}

// ---------------- output projection: dense remap, 128x128 tiles ----------------
// Valid (b, mtile, ntile): mtile < scp128(b)/128, ntile < 8. Packed densely.
__global__ __launch_bounds__(256, 4) void gemm_out_k(
    const short* __restrict__ A, const short* __restrict__ Bm, float* __restrict__ C,
    const float* __restrict__ biasv, const int* __restrict__ sidx, const int* __restrict__ scnt)
{
  __shared__ short sm[16384];
  const int tid = threadIdx.x;
  const int wv = tid>>6, lane = tid&63, quad = lane>>4, l16 = lane&15;
  int mt[4], CO[5];
  {
    int co = 0;
    #pragma unroll
    for (int b2=0; b2<4; b2++){
      mt[b2] = ((scnt[b2] + 127) & ~127) >> 7;
      CO[b2] = co; co += mt[b2]*8;
    }
    CO[4] = co;
  }
  const int g = blockIdx.x;
  if (g >= CO[4]) return;
  int b = 0;
  while (b < 3 && g >= CO[b+1]) b++;
  int local = g - CO[b];
  int mtile = local >> 3, ntile = local & 7;
  const int jloc = mtile*128, n0 = ntile*128;
  const int m0 = b*Sn + jloc;
  const int cnt = scnt[b];
  const int* sx = sidx + (size_t)b*Sn;
  const int wm = (wv>>1)*64, wn = (wv&1)*64;
  int srw[2], sgc[2];
  #pragma unroll
  for (int i=0; i<2; i++){
    int idx = i*256 + tid;
    srw[i] = 2*(idx>>3) + (idx&1);
    sgc[i] = (((idx>>1)&3) ^ ((idx>>3)&3))*8;
  }
  auto stage = [&](int kt, short* dA, short* dB){
    int k0 = kt*32;
    #pragma unroll
    for (int i=0; i<2; i++){
      int idx = i*256 + tid;
      async16(A  + (size_t)(m0+srw[i])*En + k0 + sgc[i], dA + idx*8);
      async16(Bm + (size_t)(n0+srw[i])*En + k0 + sgc[i], dB + idx*8);
    }
  };
  fx4 acc[4][4] = {};
  int roffA[4], roffB[4];
  #pragma unroll
  for (int mi=0; mi<4; mi++){
    int row = wm + mi*16 + l16;
    roffA[mi] = (row>>1)*64 + ((quad ^ ((row>>1)&3))*16) + (row&1)*8;
    int rowb = wn + mi*16 + l16;
    roffB[mi] = (rowb>>1)*64 + ((quad ^ ((rowb>>1)&3))*16) + (rowb&1)*8;
  }
  auto compute = [&](const short* cA, const short* cB){
    short8 af[4], bfr[4];
    #pragma unroll
    for (int mi=0; mi<4; mi++) af[mi]  = *(const short8*)&cA[roffA[mi]];
    #pragma unroll
    for (int ni=0; ni<4; ni++) bfr[ni] = *(const short8*)&cB[roffB[ni]];
    #pragma unroll
    for (int mi=0; mi<4; mi++)
      #pragma unroll
      for (int ni=0; ni<4; ni++)
        acc[mi][ni] = mfma_h(af[mi], bfr[ni], acc[mi][ni]);
  };
  stage(0, sm, sm+8192);
  for (int kt2=0; kt2<16; kt2++){
    stage(2*kt2+1, sm+4096, sm+12288);
    WAIT_VM4;
    __builtin_amdgcn_s_barrier(); FENCE;
    compute(sm, sm+8192);
    WAIT_LGKM0;
    __builtin_amdgcn_s_barrier(); FENCE;
    if (kt2 < 15){ stage(2*kt2+2, sm, sm+8192); WAIT_VM4; }
    else         { WAIT_VM0; }
    __builtin_amdgcn_s_barrier(); FENCE;
    compute(sm+4096, sm+12288);
    WAIT_LGKM0;
    __builtin_amdgcn_s_barrier(); FENCE;
  }
  #pragma unroll
  for (int mi=0; mi<4; mi++)
    #pragma unroll
    for (int ni=0; ni<4; ni++)
      #pragma unroll
      for (int rg=0; rg<4; rg++){
        int j = jloc + wm + mi*16 + quad*4 + rg;
        if (j < cnt){
          int row = b*Sn + sx[j];
          int col = n0 + wn + ni*16 + l16;
          C[(size_t)row*En + col] = acc[mi][ni][rg] + biasv[col];
        }
      }
}

// ---------------- flash attention v8: compacted + XCD-grouped block mapping ----------
// 1-D grid of 1024. bh = (lid&7)*8 + ((lid>>3)&7), qt = lid>>6 (R10 best).
__global__ __launch_bounds__(256, 4) void flash8_k(
    const short* __restrict__ Qg, const short* __restrict__ Kg, const short* __restrict__ Vtg,
    const _Float16* __restrict__ biasB, const float* __restrict__ a1Lv,
    const int* __restrict__ scnt, short* __restrict__ AO)
{
  __shared__ short smem[2][2][64*64];   // [buf][K/Vt][tile] = 32 KB
  const int tid = threadIdx.x, wv = tid>>6, lane = tid&63;
  const int l32 = lane&31, hi = lane>>5;
  const int lid = blockIdx.x;
  const int bh = (lid & 7)*8 + ((lid >> 3) & 7);
  const int q0 = (lid >> 6)*128;
  const int b = bh >> 4, h = bh & 15;
  const int cnt = scnt[b];
  const int NT = ((cnt + 63) & ~63) >> 6;       // compacted key tile count
  const int scp128 = (cnt + 127) & ~127;
  if (q0 >= scp128) return;                     // compacted query blocks only
  const int sC = scp128;                        // compacted biasT column stride
  const short* Qb  = Qg  + (size_t)b*Sn*En + h*64;
  const int q = q0 + wv*32 + l32;
  const float a1L = a1Lv[b*Sn + q];

  // thread-fixed staging coords (rnd1 = rnd0 + 32 rows; col swizzle identical)
  const int r0 = tid>>3, c0 = (tid&7) ^ (r0&7);
  const int kr0 = (r0 & 51) | ((r0&4)<<1) | ((r0&8)>>1);   // s-bits 2<->3 swap
  const short* kA = Kg  + (size_t)b*Sn*En + h*64 + (size_t)kr0*En + c0*8;
  const short* vA = Vtg + (size_t)(b*Hn + h)*64*Sn + (size_t)r0*Sn + c0*8;
  const _Float16* bP = biasB + (size_t)b*Sn*Sn + ((size_t)hi*sC + q)*8;
  const int ld0 = tid*8;   // LDS slot (shorts), rnd1 = +2048

  auto issue = [&](int buf){
    short* base = &smem[buf][0][0];
    async16(kA,             base + ld0);
    async16(kA + 32*En,     base + 2048 + ld0);
    async16(vA,             base + 4096 + ld0);
    async16(vA + 32*Sn,     base + 4096 + 2048 + ld0);
  };
  if (NT > 0){ issue(0); }
  kA += 64*En; vA += 64;

  // Q B-frags: B[n=q][k = c*16 + hi*8 + j]
  short8 qf[4];
  #pragma unroll
  for (int c=0; c<4; c++)
    qf[c] = *(const short8*)(Qb + (size_t)q*En + c*16 + hi*8);

  // loop-invariant LDS read offsets (shorts), K plane / V plane
  int koff[2][4], voff[2][4];
  #pragma unroll
  for (int t=0; t<2; t++){
    int m = t*32 + l32;
    #pragma unroll
    for (int c=0; c<4; c++)
      koff[t][c] = m*64 + (((c*2 + hi) ^ (m&7))*8);
  }
  #pragma unroll
  for (int ds=0; ds<2; ds++){
    int rv = ds*32 + l32;
    #pragma unroll
    for (int sc=0; sc<4; sc++)
      voff[ds][sc] = 4096 + rv*64 + (((sc*2 + hi) ^ (rv&7))*8);
  }

  fp16x2 one2; one2[0] = (__fp16)1.0f; one2[1] = (__fp16)1.0f;
  fx16 o0 = {}, o1 = {};
  float psum = 0.f;

  for (int T=0; T<NT; T++){
    __syncthreads();                      // tile T resident; other buf free
    const short* base = &smem[T&1][0][0];
    if (T < NT-1){ issue((T&1)^1); kA += 64*En; vA += 64; }

    #pragma unroll
    for (int t=0; t<2; t++){              // s-strip of 32
      half8 bch[2];
      #pragma unroll
      for (int c2=0; c2<2; c2++)
        bch[c2] = *(const half8*)(bP + (size_t)(t*4 + c2*2)*sC*8);
      fx16 sa = {};
      #pragma unroll
      for (int c=0; c<4; c++){
        short8 ka = *(const short8*)(base + koff[t][c]);
        sa = mfma32h(ka, qf[c], sa);
      }
      #pragma unroll
      for (int c2=0; c2<2; c2++){
        fp16x2 pk_[4];
        #pragma unroll
        for (int jj=0; jj<4; jj++){
          float pa = __builtin_amdgcn_exp2f(fmaf(sa[c2*8 + jj*2],     a1L, (float)bch[c2][jj*2]));
          float pb = __builtin_amdgcn_exp2f(fmaf(sa[c2*8 + jj*2 + 1], a1L, (float)bch[c2][jj*2+1]));
          pk_[jj] = __builtin_amdgcn_cvt_pkrtz(pa, pb);
          psum = __builtin_amdgcn_fdot2(pk_[jj], one2, psum, false);
        }
        ix4 fr = { __builtin_bit_cast(int, pk_[0]), __builtin_bit_cast(int, pk_[1]),
                   __builtin_bit_cast(int, pk_[2]), __builtin_bit_cast(int, pk_[3]) };
        short8 pfr = __builtin_bit_cast(short8, fr);
        int sc = t*2 + c2;
        #pragma unroll
        for (int ds=0; ds<2; ds++){
          short8 va = *(const short8*)(base + voff[ds][sc]);
          if (ds == 0) o0 = mfma32h(va, pfr, o0);
          else         o1 = mfma32h(va, pfr, o1);
        }
      }
    }
    bP += (size_t)8*sC*8;
  }

  psum += __shfl_xor(psum, 32, 64);
  float linv = 1.f/fmaxf(psum, 1e-30f);

  // epilogue: stage o^T -> LDS [q][d] (stride 72), then coalesced b128 stores
  __syncthreads();
  short* stage = &smem[0][0][0] + wv*2304;   // 32*72 shorts per wave
  #pragma unroll
  for (int ds=0; ds<2; ds++){
    const fx16& o = ds ? o1 : o0;
    #pragma unroll
    for (int rq=0; rq<4; rq++){
      int d0 = ds*32 + rq*8 + hi*4;
      short4v pk;
      #pragma unroll
      for (int j=0; j<4; j++) pk[j] = f2h(o[rq*4 + j]*linv);
      *(short4v*)&stage[l32*72 + d0] = pk;
    }
  }
  short* AOb = AO + (size_t)b*Sn*En + h*64;
  #pragma unroll
  for (int rnd=0; rnd<4; rnd++){
    int idx = rnd*64 + lane;
    int r = idx>>3, ch = idx&7;
    fx4 val = *(const fx4*)&stage[r*72 + ch*8];
    *(fx4*)(AOb + (size_t)(q0 + wv*32 + r)*En + ch*8) = val;
  }
}

extern "C" void kernel_launch(void* const* d_in, const int* in_sizes, int n_in,
                              void* d_out, int out_size, void* d_ws, size_t ws_size,
                              hipStream_t stream)
{
  const float* his     = (const float*)d_in[0];
  const int*   mask    = (const int*)  d_in[1];
  const float* mu      = (const float*)d_in[2];
  const float* sigma   = (const float*)d_in[3];
  const float* assign  = (const float*)d_in[4];
  const float* explore = (const float*)d_in[5];
  const float* exploit = (const float*)d_in[6];
  const float* Wq = (const float*)d_in[7];  const float* bq = (const float*)d_in[8];
  const float* Wk = (const float*)d_in[9];  const float* bk = (const float*)d_in[10];
  const float* Wv = (const float*)d_in[11]; const float* bv = (const float*)d_in[12];
  const float* Wo = (const float*)d_in[13]; const float* bo = (const float*)d_in[14];

  char* w = (char*)d_ws;
  size_t off = 0;
  auto alloc = [&](size_t bytes){ void* p = w + off; off += (bytes + 255) & ~(size_t)255; return p; };
  short*     Xc    = (short*)alloc((size_t)BSn*En*2);
  short*     WQKV  = (short*)alloc((size_t)3*En*En*2);
  short*     Wof   = (short*)alloc((size_t)En*En*2);
  short*     Qc    = (short*)alloc((size_t)BSn*En*2);
  short*     Kc    = (short*)alloc((size_t)BSn*En*2);
  short*     Vtc   = (short*)alloc((size_t)BSn*En*2);
  short*     AO    = (short*)alloc((size_t)BSn*En*2);
  _Float16*  F     = (_Float16*)alloc((size_t)BSn*128*2);
  _Float16*  G     = (_Float16*)alloc((size_t)BSn*128*2);
  _Float16*  biasT = (_Float16*)alloc((size_t)Bn*Sn*Sn*2);
  float*     a1Lc  = (float*)alloc((size_t)BSn*4);
  int*       sidx  = (int*)alloc((size_t)BSn*4);
  int*       scnt  = (int*)alloc(256);
  (void)ws_size; (void)in_sizes; (void)n_in; (void)out_size;

  fused_prep_k<<<2816, 256, 0, stream>>>(his, sidx, scnt, mu, sigma, assign, explore, exploit,
                                         mask, Wq, Wk, Wv, Wo, WQKV, Wof, Xc, a1Lc, F, G,
                                         (float*)d_out);
  fused_gemm_k<<<2560, 256, 0, stream>>>(Xc, WQKV, Qc, Kc, Vtc, bq, bk, bv,
                                         (const _Float16*)G, (const _Float16*)F,
                                         biasT, a1Lc, sidx, scnt);
  flash8_k<<<1024, 256, 0, stream>>>(Qc, Kc, Vtc, biasT, a1Lc, scnt, AO);
  gemm_out_k<<<512, 256, 0, stream>>>(AO, Wof, (float*)d_out, bo, sidx, scnt);
}